// Round 4
// baseline (6367.775 us; speedup 1.0000x reference)
//
#include <hip/hip_runtime.h>

typedef __attribute__((ext_vector_type(8))) short short8;
typedef __attribute__((ext_vector_type(4))) float f32x4;
typedef unsigned short u16;
typedef unsigned int u32;
typedef unsigned long long u64;

// Shapes: B=16, T_ENC=256, T_DEC=64, N_MEL=80, ENC=512, ARNN=DRNN=1024,
// PRENET=256, ATTN_DIM=128, LOC_F=32, LOC_K=31
// attn LSTM K = 1792 (56 tiles of 32); dec K = 2560 (80 tiles)
// MFMA 16x16x32 bf16; C/D: col=lane&15, row=(lane>>4)*4+reg  [HW-verified]

// ---------------- workspace byte offsets ----------------
static constexpr size_t OFF_WFA   = 0;                 // 14,680,064
static constexpr size_t OFF_WFD   = 14680064;          // 20,971,520
static constexpr size_t OFF_PREF  = 35651584;          // 524,288
static constexpr size_t OFF_QWB   = 36175872;          // 262,144
static constexpr size_t OFF_MWT   = 36438016;          // 262,144
static constexpr size_t OFF_BA    = 36700160;          // 16,384
static constexpr size_t OFF_BD    = 36716544;          // 16,384
static constexpr size_t OFF_PM    = 36732928;          // 2,097,152  pmT[b][d][tt] f32
static constexpr size_t OFF_CTXF  = 38830080;          // 65*512*16*4 = 2,129,920
static constexpr size_t OFF_DHF   = 40960000;          // 65*1024*16*4 = 4,259,840
static constexpr size_t OFF_AHFD  = 45219840;          // 65*32*1024 = 2,129,920
static constexpr size_t OFF_CTXFD = 47349760;          // 65*16*1024 = 1,064,960
static constexpr size_t OFF_MF16  = 48414720;          // 16*256*512*2 = 4,194,304
// ---- zero-init region ----
static constexpr size_t OFF_XBUFA = 52609024;          // 2*48*1024 = 98,304
static constexpr size_t OFF_DHB   = 52707328;          // 2*32*1024 = 65,536
static constexpr size_t OFF_AHN   = 52772864;          // 16*1024*4 = 65,536
static constexpr size_t OFF_BAR   = 52838400;          // 4,096 (counters + flags)
static constexpr size_t OFF_END   = 52842496;
static constexpr size_t ZERO_BYTES = OFF_END - OFF_XBUFA;  // 233,472

__device__ __forceinline__ float sigmf(float x) { return 1.f / (1.f + expf(-x)); }
__device__ __forceinline__ float tanh_fast(float x) {
  float e2 = __expf(2.f * x);
  return 1.f - 2.f / (e2 + 1.f);
}
__device__ __forceinline__ u16 f2bf(float f) {
  u32 u = __float_as_uint(f);
  return (u16)((u + 0x7FFFu + ((u >> 16) & 1u)) >> 16);
}
__device__ __forceinline__ float bf2f(u16 x) { return __uint_as_float(((u32)x) << 16); }

// agent-scope (LLC, bypass non-coherent L1/L2) helpers
__device__ __forceinline__ short8 ld_frag_agent(const void* ptr) {
  const u64* q = (const u64*)ptr;
  u64 lo = __hip_atomic_load(q, __ATOMIC_RELAXED, __HIP_MEMORY_SCOPE_AGENT);
  u64 hi = __hip_atomic_load(q + 1, __ATOMIC_RELAXED, __HIP_MEMORY_SCOPE_AGENT);
  union { u64 q2[2]; short8 s; } u;
  u.q2[0] = lo; u.q2[1] = hi;
  return u.s;
}
__device__ __forceinline__ void st_u16_agent(u16* p, u16 v) {
  __hip_atomic_store(p, v, __ATOMIC_RELAXED, __HIP_MEMORY_SCOPE_AGENT);
}
__device__ __forceinline__ void st_f32_agent(float* p, float v) {
  __hip_atomic_store(p, v, __ATOMIC_RELAXED, __HIP_MEMORY_SCOPE_AGENT);
}

// master/broadcast grid barrier: arrive on 16 striped counters; master (bk 255)
// detects sum==256*epoch and publishes epoch to 16 striped flags; others poll
// ONE flag line. No L2 flush/invalidate anywhere (all traffic agent-scope).
__device__ __forceinline__ void gbar(u32* bar, int bk, int th, u32 epoch) {
  __syncthreads();   // drains vmcnt -> all agent stores visible at LLC
  if (th == 0) {
    __hip_atomic_fetch_add(bar + (bk & 15) * 16, 1u, __ATOMIC_RELAXED, __HIP_MEMORY_SCOPE_AGENT);
    if (bk == 255) {
      u32 target = epoch * 256u;
      for (;;) {
        u32 sum = 0;
#pragma unroll
        for (int i = 0; i < 16; ++i)
          sum += __hip_atomic_load(bar + i * 16, __ATOMIC_RELAXED, __HIP_MEMORY_SCOPE_AGENT);
        if (sum >= target) break;
        __builtin_amdgcn_s_sleep(1);
      }
#pragma unroll
      for (int i = 0; i < 16; ++i)
        __hip_atomic_store(bar + 256 + i * 16, epoch, __ATOMIC_RELAXED, __HIP_MEMORY_SCOPE_AGENT);
    } else {
      u32* flag = bar + 256 + (bk & 15) * 16;
      while (__hip_atomic_load(flag, __ATOMIC_RELAXED, __HIP_MEMORY_SCOPE_AGENT) < epoch)
        __builtin_amdgcn_s_sleep(1);
    }
  }
  __syncthreads();
}

// ---------------- prep: LSTM weights -> bf16 A-fragment layout ----------------
__global__ void k_wfrag(const float* __restrict__ Wih, const float* __restrict__ Whh,
                        char* __restrict__ dst, int NT, int Kih) {
  int idx = blockIdx.x * 256 + threadIdx.x;   // (bk*NT + s)*64 + l
  int l = idx & 63;
  int st = idx >> 6;
  int s = st % NT, bk = st / NT;
  int r = l & 15, kg = l >> 4;
  int j = (r >> 2) * 1024 + bk * 4 + (r & 3);
  int k0 = s * 32 + kg * 8;
  const float* src = (k0 < Kih) ? (Wih + (size_t)j * Kih + k0)
                                : (Whh + (size_t)j * 1024 + (k0 - Kih));
  short8 v;
#pragma unroll
  for (int e = 0; e < 8; ++e) v[e] = (short)f2bf(src[e]);
  *(short8*)(dst + (size_t)idx * 16) = v;
}

// ---------------- prep: memW^T, combined biases, qW bf16 ----------------
__global__ void k_smallprep(const float* __restrict__ memW,
                            const float* __restrict__ abih, const float* __restrict__ abhh,
                            const float* __restrict__ dbih, const float* __restrict__ dbhh,
                            const float* __restrict__ qW, char* __restrict__ wsb) {
  int idx = blockIdx.x * 256 + threadIdx.x;
  if (idx < 65536) {
    int k = idx >> 7, d = idx & 127;
    ((float*)(wsb + OFF_MWT))[idx] = memW[d * 512 + k];
  } else if (idx < 69632) {
    int j = idx - 65536;
    ((float*)(wsb + OFF_BA))[j] = abih[j] + abhh[j];
  } else if (idx < 73728) {
    int j = idx - 69632;
    ((float*)(wsb + OFF_BD))[j] = dbih[j] + dbhh[j];
  } else if (idx < 204800) {
    int j = idx - 73728;
    ((u16*)(wsb + OFF_QWB))[j] = f2bf(qW[j]);
  }
}

// ---------------- prep: memory -> f16 copy [b][tt][d] ----------------
__global__ void k_memf16(const float* __restrict__ memory, char* __restrict__ wsb) {
  size_t i = (size_t)blockIdx.x * 256 + threadIdx.x;   // 524,288 float4s
  float4 v = ((const float4*)memory)[i];
  union { _Float16 h[4]; u64 q; } u;
  u.h[0] = (_Float16)v.x; u.h[1] = (_Float16)v.y;
  u.h[2] = (_Float16)v.z; u.h[3] = (_Float16)v.w;
  ((u64*)(wsb + OFF_MF16))[i] = u.q;
}

// ---------------- prep: prenet -> bf16 B-fragment layout per step ----------------
__global__ void k_prenet(const float* __restrict__ dec_in,
                         const float* __restrict__ W1, const float* __restrict__ b1,
                         const float* __restrict__ W2, const float* __restrict__ b2,
                         char* __restrict__ wsb) {
  int s = blockIdx.x, b = blockIdx.y, th = threadIdx.x;
  __shared__ float frame[80];
  __shared__ float h1[256];
  if (th < 80) frame[th] = (s == 0) ? 0.f : dec_in[(b * 80 + th) * 64 + (s - 1)];
  __syncthreads();
  float a = b1[th];
  const float* w1r = W1 + th * 80;
  for (int m = 0; m < 80; ++m) a += w1r[m] * frame[m];
  h1[th] = fmaxf(a, 0.f);
  __syncthreads();
  float a2 = b2[th];
  const float* w2r = W2 + th * 256;
  for (int i = 0; i < 256; ++i) a2 += w2r[i] * h1[i];
  float pre = fmaxf(a2, 0.f);
  int k = th;
  ((u16*)(wsb + OFF_PREF))[(((size_t)s * 8 + (k >> 5)) * 64 + ((k >> 3) & 3) * 16 + b) * 8 + (k & 7)] = f2bf(pre);
}

// ---------------- prep: processed_memory, TRANSPOSED pmT[b][d][tt] ----------------
__global__ void k_pm(const float* __restrict__ memory, char* __restrict__ wsb) {
  int bk = blockIdx.x, th = threadIdx.x;
  int b = bk >> 4, t0 = (bk & 15) * 16;
  __shared__ float mrow[16 * 512];
  for (int i = 0; i < 8; ++i) {
    int fi4 = i * 256 + th;
    int tl = fi4 >> 7, k4 = (fi4 & 127) << 2;
    *(float4*)&mrow[tl * 512 + k4] =
        *(const float4*)&memory[((size_t)(b * 256 + t0 + tl)) * 512 + k4];
  }
  __syncthreads();
  int d = th & 127, tl0 = th >> 7;
  float acc[8] = {};
  const float* mWT = (const float*)(wsb + OFF_MWT);
  float* pmw = (float*)(wsb + OFF_PM);
  for (int k = 0; k < 512; ++k) {
    float w = mWT[k * 128 + d];
#pragma unroll
    for (int i = 0; i < 8; ++i) acc[i] += w * mrow[(tl0 + i * 2) * 512 + k];
  }
  for (int i = 0; i < 8; ++i)
    pmw[((size_t)b * 128 + d) * 256 + (t0 + tl0 + i * 2)] = acc[i];
}

struct KParams {
  const float* memory;
  const int* mlen;
  const float* convW;
  const float* ldW;
  const float* attnv;
  const float* projW;
  const float* projb;
  const float* gateW;
  const float* gateb;
  char* wsb;
  float* out;
};

// ---------------- main persistent kernel ----------------
__global__ void __launch_bounds__(512, 2) k_main(KParams p) {
  const int th = threadIdx.x;
  const int bk = blockIdx.x;
  char* wsb = p.wsb;
  const int l = th & 63, w = th >> 6;
  u32* bar = (u32*)(wsb + OFF_BAR);
  u32 ep = 0;

  __shared__ float smC[4608];
  __shared__ float s2q[128], s2v[128];
  __shared__ float s2ldw[4608];               // [128][36] f32 (16B-aligned rows)
  __shared__ float s_conv[8448];              // [256][33]
  __shared__ __align__(16) float s2ah[1024];
  __shared__ float s_e[256], s3wr[4];
  __shared__ float s1cw[1984];                // convW 32*62
  __shared__ float s_aw[256], s_awc[256];     // persistent attention state (per-b block)

  const float* pmT = (const float*)(wsb + OFF_PM);
  const u16* qwb = (const u16*)(wsb + OFF_QWB);

  // persistent LDS staging (step-invariant)
  for (int i = th; i < 1984; i += 512) s1cw[i] = p.convW[i];
  for (int i = th; i < 4096; i += 512) s2ldw[(i >> 5) * 36 + (i & 31)] = p.ldW[i];
  if (th < 128) s2v[th] = p.attnv[th];
  if (th < 256) { s_aw[th] = 0.f; s_awc[th] = 0.f; }

  // per-thread combined bias (attn rows for th<256, dec rows for th>=256)
  float bias_r;
  {
    int rr = (th & 255) >> 4;
    const float* bsrc = (const float*)(wsb + (th < 256 ? OFF_BA : OFF_BD));
    bias_r = bsrc[(rr >> 2) * 1024 + bk * 4 + (rr & 3)];
  }
  int len = 0;
  if (bk < 16) len = p.mlen[bk];
  float cA = 0.f, cD = 0.f;   // register cell states (cA: th<64; cD: th in [64,128))

  // preload step-invariant A-fragments: attn 7 tiles/wave, dec 10 tiles/wave
  short8 afA[7], afD[10];
  {
    const char* wfa = wsb + OFF_WFA;
    const char* wfd = wsb + OFF_WFD;
#pragma unroll
    for (int i = 0; i < 7; ++i)
      afA[i] = *(const short8*)(wfa + (((size_t)bk * 56 + (w + 8 * i)) * 64 + l) * 16);
#pragma unroll
    for (int i = 0; i < 10; ++i)
      afD[i] = *(const short8*)(wfd + (((size_t)bk * 80 + (w + 8 * i)) * 64 + l) * 16);
  }
  __syncthreads();

  // ======== fused loop: interval t does attn-LSTM(t) + dec-LSTM(t-1) =========
  for (int t = 0; t <= 64; ++t) {
    const bool doA = (t < 64), doD = (t > 0);
    const int par = t & 1, par2 = par ^ 1;

    short8 bfr[7], xv[10];
    if (doA) {
      bfr[0] = *(const short8*)(wsb + OFF_PREF + (((size_t)t * 8 + w) * 64 + l) * 16);
#pragma unroll
      for (int i = 1; i < 7; ++i)
        bfr[i] = ld_frag_agent(wsb + OFF_XBUFA + (size_t)par * 49152 +
                               ((size_t)(w + 8 * i - 8) * 64 + l) * 16);
    }
    if (doD) {
      const int ptd = (t - 1) & 1;
#pragma unroll
      for (int i = 0; i < 4; ++i)
        xv[i] = ld_frag_agent(wsb + OFF_AHFD + (((size_t)t * 32 + (w + 8 * i)) * 64 + l) * 16);
#pragma unroll
      for (int i = 4; i < 6; ++i)
        xv[i] = ld_frag_agent(wsb + OFF_CTXFD + (((size_t)t * 16 + (w + 8 * i - 32)) * 64 + l) * 16);
#pragma unroll
      for (int i = 6; i < 10; ++i)
        xv[i] = ld_frag_agent(wsb + OFF_DHB + (size_t)ptd * 32768 +
                              ((size_t)(w + 8 * i - 48) * 64 + l) * 16);
    }
    f32x4 accA = {0.f, 0.f, 0.f, 0.f}, accD = {0.f, 0.f, 0.f, 0.f};
    if (doA) {
#pragma unroll
      for (int i = 0; i < 7; ++i)
        accA = __builtin_amdgcn_mfma_f32_16x16x32_bf16(afA[i], bfr[i], accA, 0, 0, 0);
#pragma unroll
      for (int r4 = 0; r4 < 4; ++r4)
        smC[w * 256 + ((l >> 4) * 4 + r4) * 16 + (l & 15)] = accA[r4];
    }
    if (doD) {
#pragma unroll
      for (int i = 0; i < 10; ++i)
        accD = __builtin_amdgcn_mfma_f32_16x16x32_bf16(afD[i], xv[i], accD, 0, 0, 0);
#pragma unroll
      for (int r4 = 0; r4 < 4; ++r4)
        smC[2048 + w * 256 + ((l >> 4) * 4 + r4) * 16 + (l & 15)] = accD[r4];
    }
    __syncthreads();
    if (th < 256) {
      if (doA) {
        int r = th >> 4, b2 = th & 15;
        float s = 0.f;
#pragma unroll
        for (int w2 = 0; w2 < 8; ++w2) s += smC[w2 * 256 + r * 16 + b2];
        smC[4096 + r * 16 + b2] = s + bias_r;
      }
    } else if (doD) {
      int r = (th - 256) >> 4, b2 = th & 15;
      float s = 0.f;
#pragma unroll
      for (int w2 = 0; w2 < 8; ++w2) s += smC[2048 + w2 * 256 + r * 16 + b2];
      smC[4352 + r * 16 + b2] = s + bias_r;
    }
    __syncthreads();
    if (doA && th < 64) {   // attn pointwise
      int ul = th >> 4, b = th & 15, u = bk * 4 + ul;
      float gi = smC[4096 + ul * 16 + b];
      float gf = smC[4096 + (4 + ul) * 16 + b];
      float gc = smC[4096 + (8 + ul) * 16 + b];
      float go = smC[4096 + (12 + ul) * 16 + b];
      float c2 = sigmf(gf) * cA + sigmf(gi) * tanhf(gc);
      float h2 = sigmf(go) * tanhf(c2);
      cA = c2;
      st_f32_agent((float*)(wsb + OFF_AHN) + b * 1024 + u, h2);
      u16 hb = f2bf(h2);
      st_u16_agent((u16*)(wsb + OFF_XBUFA) + (size_t)par2 * 24576 +
                   (((size_t)(16 + (u >> 5)) * 64 + ((u >> 3) & 3) * 16 + b) * 8 + (u & 7)), hb);
      st_u16_agent((u16*)(wsb + OFF_AHFD) +
                   ((((size_t)(t + 1) * 32 + (u >> 5)) * 64 + ((u >> 3) & 3) * 16 + b) * 8 + (u & 7)), hb);
    }
    if (doD && th >= 64 && th < 128) {   // dec pointwise (step t-1)
      int ul = (th >> 4) - 4, b = th & 15, u = bk * 4 + ul;
      float gi = smC[4352 + ul * 16 + b];
      float gf = smC[4352 + (4 + ul) * 16 + b];
      float gc = smC[4352 + (8 + ul) * 16 + b];
      float go = smC[4352 + (12 + ul) * 16 + b];
      float c2 = sigmf(gf) * cD + sigmf(gi) * tanhf(gc);
      float h2 = sigmf(go) * tanhf(c2);
      cD = c2;
      st_f32_agent((float*)(wsb + OFF_DHF) + ((size_t)t * 1024 + u) * 16 + b, h2);
      st_u16_agent((u16*)(wsb + OFF_DHB) + (size_t)par * 16384 +
                   (((size_t)(u >> 5) * 64 + ((u >> 3) & 3) * 16 + b) * 8 + (u & 7)), f2bf(h2));
    }
    gbar(bar, bk, th, ++ep);

    if (t < 64) {
      // ---- Phase B: full attention for one b per block (16 active blocks) ----
      if (bk < 16) {
        const int b = bk;
        {
          const u64* src = (const u64*)((float*)(wsb + OFF_AHN) + (size_t)b * 1024);
          ((u64*)s2ah)[th] = __hip_atomic_load(src + th, __ATOMIC_RELAXED, __HIP_MEMORY_SCOPE_AGENT);
        }
        __syncthreads();
        {  // query partials
          int d = th & 127, part = th >> 7;
          const u16* qr = qwb + d * 1024 + part * 256;
          const float* ah = s2ah + part * 256;
          float qa = 0.f;
          for (int kk = 0; kk < 256; kk += 8) {
            short8 v = *(const short8*)(qr + kk);
#pragma unroll
            for (int e = 0; e < 8; ++e) qa += bf2f((u16)v[e]) * ah[kk + e];
          }
          smC[part * 128 + d] = qa;
        }
        __syncthreads();
        if (th < 128) s2q[th] = smC[th] + smC[128 + th] + smC[256 + th] + smC[384 + th];
        // conv single-pass, len-bounded
        {
          int jmax = (len + 15) >> 4;
          for (int j = 0; j < jmax; ++j) {
            int idx = j * 512 + th, tt = idx >> 5, f = idx & 31;
            float a = 0.f;
            const float* w0 = s1cw + f * 62;
#pragma unroll
            for (int kk = 0; kk < 31; ++kk) {
              int pos = tt + kk - 15;
              bool ok = (pos >= 0 && pos < 256);
              float awv = ok ? s_aw[pos] : 0.f;
              float awcv = ok ? s_awc[pos] : 0.f;
              a += awv * w0[kk] + awcv * w0[31 + kk];
            }
            s_conv[tt * 33 + f] = a;
          }
        }
        __syncthreads();
        {  // energies: thread = (tt, d-half of 64)
          int tt = th >> 1, dbase = (th & 1) << 6;
          float e = 0.f;
          if (tt < len) {
            float cvr[32];
            const float* cv = s_conv + tt * 33;
#pragma unroll
            for (int f = 0; f < 32; ++f) cvr[f] = cv[f];
            const float* pmr = pmT + ((size_t)b * 128 + dbase) * 256 + tt;
#pragma unroll 2
            for (int jd = 0; jd < 64; ++jd) {
              int d2 = dbase + jd;
              float sacc = s2q[d2] + pmr[(size_t)jd * 256];
              const float4* lw4 = (const float4*)(s2ldw + d2 * 36);
#pragma unroll
              for (int f4 = 0; f4 < 8; ++f4) {
                float4 lw = lw4[f4];
                sacc += cvr[f4 * 4] * lw.x + cvr[f4 * 4 + 1] * lw.y +
                        cvr[f4 * 4 + 2] * lw.z + cvr[f4 * 4 + 3] * lw.w;
              }
              e += s2v[d2] * tanh_fast(sacc);
            }
          }
          e += __shfl_xor(e, 1);
          if ((th & 1) == 0) s_e[tt] = (tt < len) ? __expf(e) : 0.f;
        }
        __syncthreads();
        if (th < 256) {
          float v0 = s_e[th];
#pragma unroll
          for (int off = 32; off; off >>= 1) v0 += __shfl_xor(v0, off);
          if ((th & 63) == 0) s3wr[th >> 6] = v0;
        }
        __syncthreads();
        float rden = 1.f / (s3wr[0] + s3wr[1] + s3wr[2] + s3wr[3]);
        if (th < 256) {
          float a = s_e[th] * rden;
          s_aw[th] = a;
          s_awc[th] += a;
          p.out[82944 + ((size_t)(b * 64 + t)) * 256 + th] = a;
        }
        __syncthreads();
        {  // context from f16 memory copy
          const int d = th;
          const _Float16* mb = (const _Float16*)(wsb + OFF_MF16) + (size_t)b * 131072 + d;
          float a0 = 0.f, a1 = 0.f, a2 = 0.f, a3 = 0.f;
          int lim4 = (len + 3) & ~3;
          for (int tt = 0; tt < lim4; tt += 4) {
            a0 += s_aw[tt] * (float)mb[(size_t)tt * 512];
            a1 += s_aw[tt + 1] * (float)mb[(size_t)(tt + 1) * 512];
            a2 += s_aw[tt + 2] * (float)mb[(size_t)(tt + 2) * 512];
            a3 += s_aw[tt + 3] * (float)mb[(size_t)(tt + 3) * 512];
          }
          float ctxv = (a0 + a1) + (a2 + a3);
          st_f32_agent((float*)(wsb + OFF_CTXF) + ((size_t)(t + 1) * 512 + d) * 16 + b, ctxv);
          u16 cb2 = f2bf(ctxv);
          st_u16_agent((u16*)(wsb + OFF_XBUFA) + (size_t)par2 * 24576 +
                       (((size_t)(d >> 5) * 64 + ((d >> 3) & 3) * 16 + b) * 8 + (d & 7)), cb2);
          st_u16_agent((u16*)(wsb + OFF_CTXFD) +
                       ((((size_t)(t + 1) * 16 + (d >> 5)) * 64 + ((d >> 3) & 3) * 16 + b) * 8 + (d & 7)), cb2);
        }
      }
      gbar(bar, bk, th, ++ep);
    }
  }

  // ================= epilogue: mel + gate projections =================
  // Plain loads OK: DHF/CTXF written once via agent stores (LLC) before the
  // final barrier; any stale L1/L2 lines from a prior replay hold bitwise
  // identical values (deterministic kernel).
  {
    int t = bk & 63, pa = bk >> 6;
    const float* dh = (const float*)(wsb + OFF_DHF) + (size_t)(t + 1) * 16384;
    const float* cx = (const float*)(wsb + OFF_CTXF) + (size_t)(t + 1) * 8192;
    int lim = (pa == 3) ? 336 : 320;
    for (int idx = th; idx < lim; idx += 512) {
      if (idx < 320) {
        int mi = idx >> 4, b = idx & 15, m = pa * 20 + mi;
        const float* wr = p.projW + (size_t)m * 1536;
        float a0 = 0.f, a1 = 0.f;
#pragma unroll 8
        for (int k = 0; k < 1024; k += 2) { a0 += wr[k] * dh[k * 16 + b]; a1 += wr[k + 1] * dh[(k + 1) * 16 + b]; }
#pragma unroll 8
        for (int k = 0; k < 512; k += 2)  { a0 += wr[1024 + k] * cx[k * 16 + b]; a1 += wr[1025 + k] * cx[(k + 1) * 16 + b]; }
        p.out[((size_t)(b * 80 + m)) * 64 + t] = a0 + a1 + p.projb[m];
      } else {
        int b = idx - 320;
        float a0 = 0.f, a1 = 0.f;
#pragma unroll 8
        for (int k = 0; k < 1024; k += 2) { a0 += p.gateW[k] * dh[k * 16 + b]; a1 += p.gateW[k + 1] * dh[(k + 1) * 16 + b]; }
#pragma unroll 8
        for (int k = 0; k < 512; k += 2)  { a0 += p.gateW[1024 + k] * cx[k * 16 + b]; a1 += p.gateW[1025 + k] * cx[(k + 1) * 16 + b]; }
        p.out[81920 + b * 64 + t] = a0 + a1 + p.gateb[0];
      }
    }
  }
}

// ---------------- host launcher ----------------
extern "C" void kernel_launch(void* const* d_in, const int* in_sizes, int n_in,
                              void* d_out, int out_size, void* d_ws, size_t ws_size,
                              hipStream_t stream) {
  (void)in_sizes; (void)n_in; (void)out_size; (void)ws_size;
  const float* memory = (const float*)d_in[0];
  const float* dec_in = (const float*)d_in[1];
  const int*   mlen   = (const int*)d_in[2];
  const float* pW1    = (const float*)d_in[3];
  const float* pb1    = (const float*)d_in[4];
  const float* pW2    = (const float*)d_in[5];
  const float* pb2    = (const float*)d_in[6];
  const float* aWih   = (const float*)d_in[7];
  const float* aWhh   = (const float*)d_in[8];
  const float* abih   = (const float*)d_in[9];
  const float* abhh   = (const float*)d_in[10];
  const float* qW     = (const float*)d_in[11];
  const float* memW   = (const float*)d_in[12];
  const float* convW  = (const float*)d_in[13];
  const float* ldW    = (const float*)d_in[14];
  const float* attnv  = (const float*)d_in[15];
  const float* dWih   = (const float*)d_in[16];
  const float* dWhh   = (const float*)d_in[17];
  const float* dbih   = (const float*)d_in[18];
  const float* dbhh   = (const float*)d_in[19];
  const float* projW  = (const float*)d_in[20];
  const float* projb  = (const float*)d_in[21];
  const float* gateW  = (const float*)d_in[22];
  const float* gateb  = (const float*)d_in[23];
  char* wsb = (char*)d_ws;
  float* out = (float*)d_out;

  hipMemsetAsync(wsb + OFF_XBUFA, 0, ZERO_BYTES, stream);

  hipLaunchKernelGGL(k_wfrag, dim3(3584), dim3(256), 0, stream, aWih, aWhh, wsb + OFF_WFA, 56, 768);
  hipLaunchKernelGGL(k_wfrag, dim3(5120), dim3(256), 0, stream, dWih, dWhh, wsb + OFF_WFD, 80, 1536);
  hipLaunchKernelGGL(k_smallprep, dim3(800), dim3(256), 0, stream, memW, abih, abhh, dbih, dbhh, qW, wsb);
  hipLaunchKernelGGL(k_memf16, dim3(2048), dim3(256), 0, stream, memory, wsb);
  hipLaunchKernelGGL(k_prenet, dim3(64, 16), dim3(256), 0, stream, dec_in, pW1, pb1, pW2, pb2, wsb);
  hipLaunchKernelGGL(k_pm, dim3(256), dim3(256), 0, stream, memory, wsb);

  KParams p{memory, mlen, convW, ldW, attnv, projW, projb, gateW, gateb, wsb, out};
  void* args[] = { &p };
  hipLaunchCooperativeKernel((void*)k_main, dim3(256), dim3(512), args, 0, stream);
}

// Round 5
// 4126.970 us; speedup vs baseline: 1.5430x; 1.5430x over previous
//
#include <hip/hip_runtime.h>

typedef __attribute__((ext_vector_type(8))) short short8;
typedef __attribute__((ext_vector_type(4))) float f32x4;
typedef unsigned short u16;
typedef unsigned int u32;
typedef unsigned long long u64;

// Shapes: B=16, T_ENC=256, T_DEC=64, N_MEL=80, ENC=512, ARNN=DRNN=1024,
// PRENET=256, ATTN_DIM=128, LOC_F=32, LOC_K=31
// attn LSTM K = 1792 (56 tiles of 32); dec K = 2560 (80 tiles)
// MFMA 16x16x32 bf16; C/D: col=lane&15, row=(lane>>4)*4+reg  [HW-verified]

// ---------------- workspace byte offsets ----------------
static constexpr size_t OFF_WFA   = 0;                 // 14,680,064
static constexpr size_t OFF_WFD   = 14680064;          // 20,971,520
static constexpr size_t OFF_PREF  = 35651584;          // 524,288
static constexpr size_t OFF_QWB   = 36175872;          // 262,144
static constexpr size_t OFF_MWT   = 36438016;          // 262,144
static constexpr size_t OFF_BA    = 36700160;          // 16,384
static constexpr size_t OFF_BD    = 36716544;          // 16,384
static constexpr size_t OFF_PM    = 36732928;          // 2,097,152  pmT[b][d][tt] f32
static constexpr size_t OFF_CTXF  = 38830080;          // 65*512*16*4 = 2,129,920
static constexpr size_t OFF_DHF   = 40960000;          // 65*1024*16*4 = 4,259,840
static constexpr size_t OFF_AHFD  = 45219840;          // 65*32*1024 = 2,129,920
static constexpr size_t OFF_CTXFD = 47349760;          // 65*16*1024 = 1,064,960
static constexpr size_t OFF_MF16  = 48414720;          // 16*256*512*2 = 4,194,304
// ---- zero-init region ----
static constexpr size_t OFF_XBUFA = 52609024;          // 2*48*1024 = 98,304
static constexpr size_t OFF_DHB   = 52707328;          // 2*32*1024 = 65,536
static constexpr size_t OFF_AHN   = 52772864;          // 16*1024*4 = 65,536
static constexpr size_t OFF_BAR   = 52838400;          // 256 arrival + 256 flag lines @64B
static constexpr size_t OFF_END   = 52871168;
static constexpr size_t ZERO_BYTES = OFF_END - OFF_XBUFA;  // 262,144

__device__ __forceinline__ float sigmf(float x) { return 1.f / (1.f + expf(-x)); }
__device__ __forceinline__ float tanh_fast(float x) {
  float e2 = __expf(2.f * x);
  return 1.f - 2.f / (e2 + 1.f);
}
__device__ __forceinline__ u16 f2bf(float f) {
  u32 u = __float_as_uint(f);
  return (u16)((u + 0x7FFFu + ((u >> 16) & 1u)) >> 16);
}
__device__ __forceinline__ float bf2f(u16 x) { return __uint_as_float(((u32)x) << 16); }

// agent-scope (LLC, bypass non-coherent L1/L2) helpers
__device__ __forceinline__ short8 ld_frag_agent(const void* ptr) {
  const u64* q = (const u64*)ptr;
  u64 lo = __hip_atomic_load(q, __ATOMIC_RELAXED, __HIP_MEMORY_SCOPE_AGENT);
  u64 hi = __hip_atomic_load(q + 1, __ATOMIC_RELAXED, __HIP_MEMORY_SCOPE_AGENT);
  union { u64 q2[2]; short8 s; } u;
  u.q2[0] = lo; u.q2[1] = hi;
  return u.s;
}
__device__ __forceinline__ void st_u16_agent(u16* p, u16 v) {
  __hip_atomic_store(p, v, __ATOMIC_RELAXED, __HIP_MEMORY_SCOPE_AGENT);
}
__device__ __forceinline__ void st_f32_agent(float* p, float v) {
  __hip_atomic_store(p, v, __ATOMIC_RELAXED, __HIP_MEMORY_SCOPE_AGENT);
}
__device__ __forceinline__ u32 ld_u32_agent(const u32* p) {
  return __hip_atomic_load(p, __ATOMIC_RELAXED, __HIP_MEMORY_SCOPE_AGENT);
}
__device__ __forceinline__ void st_u32_agent(u32* p, u32 v) {
  __hip_atomic_store(p, v, __ATOMIC_RELAXED, __HIP_MEMORY_SCOPE_AGENT);
}

// Contention-free grid barrier: private arrival line per block (plain agent
// STORE of epoch, no RMW); master (bk 255) wave-scans all 256 lines with 4
// lane-parallel loads, publishes to 256 private flag lines; each block polls
// ONLY its own flag line. Max spread 1 epoch (monotonic epochs).
__device__ __forceinline__ void gbar(u32* barr, u32* flg, int bk, int th, u32 epoch) {
  __syncthreads();   // drains vmcnt -> all agent stores visible at LLC
  if (th < 64) {
    if (th == 0) st_u32_agent(barr + bk * 16, epoch);
    if (bk == 255) {
      for (;;) {
        u32 m0 = ld_u32_agent(barr + th * 16);
        u32 m1 = ld_u32_agent(barr + (th + 64) * 16);
        u32 m2 = ld_u32_agent(barr + (th + 128) * 16);
        u32 m3 = ld_u32_agent(barr + (th + 192) * 16);
        u32 mn01 = (m0 < m1) ? m0 : m1;
        u32 mn23 = (m2 < m3) ? m2 : m3;
        u32 mn = (mn01 < mn23) ? mn01 : mn23;
        if (__all(mn >= epoch)) break;
      }
      st_u32_agent(flg + th * 16, epoch);
      st_u32_agent(flg + (th + 64) * 16, epoch);
      st_u32_agent(flg + (th + 128) * 16, epoch);
      st_u32_agent(flg + (th + 192) * 16, epoch);
    } else if (th == 0) {
      while (ld_u32_agent(flg + bk * 16) < epoch) {}
    }
  }
  __syncthreads();
}

// ---------------- prep: LSTM weights -> bf16 A-fragment layout ----------------
__global__ void k_wfrag(const float* __restrict__ Wih, const float* __restrict__ Whh,
                        char* __restrict__ dst, int NT, int Kih) {
  int idx = blockIdx.x * 256 + threadIdx.x;   // (tile*NT + s)*64 + l
  int l = idx & 63;
  int st = idx >> 6;
  int s = st % NT, tile = st / NT;
  int r = l & 15, kg = l >> 4;
  int j = (r >> 2) * 1024 + tile * 4 + (r & 3);
  int k0 = s * 32 + kg * 8;
  const float* src = (k0 < Kih) ? (Wih + (size_t)j * Kih + k0)
                                : (Whh + (size_t)j * 1024 + (k0 - Kih));
  short8 v;
#pragma unroll
  for (int e = 0; e < 8; ++e) v[e] = (short)f2bf(src[e]);
  *(short8*)(dst + (size_t)idx * 16) = v;
}

// ---------------- prep: memW^T, combined biases, qW bf16 ----------------
__global__ void k_smallprep(const float* __restrict__ memW,
                            const float* __restrict__ abih, const float* __restrict__ abhh,
                            const float* __restrict__ dbih, const float* __restrict__ dbhh,
                            const float* __restrict__ qW, char* __restrict__ wsb) {
  int idx = blockIdx.x * 256 + threadIdx.x;
  if (idx < 65536) {
    int k = idx >> 7, d = idx & 127;
    ((float*)(wsb + OFF_MWT))[idx] = memW[d * 512 + k];
  } else if (idx < 69632) {
    int j = idx - 65536;
    ((float*)(wsb + OFF_BA))[j] = abih[j] + abhh[j];
  } else if (idx < 73728) {
    int j = idx - 69632;
    ((float*)(wsb + OFF_BD))[j] = dbih[j] + dbhh[j];
  } else if (idx < 204800) {
    int j = idx - 73728;
    ((u16*)(wsb + OFF_QWB))[j] = f2bf(qW[j]);
  }
}

// ---------------- prep: memory -> f16 copy [b][tt][d] ----------------
__global__ void k_memf16(const float* __restrict__ memory, char* __restrict__ wsb) {
  size_t i = (size_t)blockIdx.x * 256 + threadIdx.x;   // 524,288 float4s
  float4 v = ((const float4*)memory)[i];
  union { _Float16 h[4]; u64 q; } u;
  u.h[0] = (_Float16)v.x; u.h[1] = (_Float16)v.y;
  u.h[2] = (_Float16)v.z; u.h[3] = (_Float16)v.w;
  ((u64*)(wsb + OFF_MF16))[i] = u.q;
}

// ---------------- prep: prenet -> bf16 B-fragment layout per step ----------------
__global__ void k_prenet(const float* __restrict__ dec_in,
                         const float* __restrict__ W1, const float* __restrict__ b1,
                         const float* __restrict__ W2, const float* __restrict__ b2,
                         char* __restrict__ wsb) {
  int s = blockIdx.x, b = blockIdx.y, th = threadIdx.x;
  __shared__ float frame[80];
  __shared__ float h1[256];
  if (th < 80) frame[th] = (s == 0) ? 0.f : dec_in[(b * 80 + th) * 64 + (s - 1)];
  __syncthreads();
  float a = b1[th];
  const float* w1r = W1 + th * 80;
  for (int m = 0; m < 80; ++m) a += w1r[m] * frame[m];
  h1[th] = fmaxf(a, 0.f);
  __syncthreads();
  float a2 = b2[th];
  const float* w2r = W2 + th * 256;
  for (int i = 0; i < 256; ++i) a2 += w2r[i] * h1[i];
  float pre = fmaxf(a2, 0.f);
  int k = th;
  ((u16*)(wsb + OFF_PREF))[(((size_t)s * 8 + (k >> 5)) * 64 + ((k >> 3) & 3) * 16 + b) * 8 + (k & 7)] = f2bf(pre);
}

// ---------------- prep: processed_memory, TRANSPOSED pmT[b][d][tt] ----------------
__global__ void k_pm(const float* __restrict__ memory, char* __restrict__ wsb) {
  int bk = blockIdx.x, th = threadIdx.x;
  int b = bk >> 4, t0 = (bk & 15) * 16;
  __shared__ float mrow[16 * 512];
  for (int i = 0; i < 8; ++i) {
    int fi4 = i * 256 + th;
    int tl = fi4 >> 7, k4 = (fi4 & 127) << 2;
    *(float4*)&mrow[tl * 512 + k4] =
        *(const float4*)&memory[((size_t)(b * 256 + t0 + tl)) * 512 + k4];
  }
  __syncthreads();
  int d = th & 127, tl0 = th >> 7;
  float acc[8] = {};
  const float* mWT = (const float*)(wsb + OFF_MWT);
  float* pmw = (float*)(wsb + OFF_PM);
  for (int k = 0; k < 512; ++k) {
    float w = mWT[k * 128 + d];
#pragma unroll
    for (int i = 0; i < 8; ++i) acc[i] += w * mrow[(tl0 + i * 2) * 512 + k];
  }
  for (int i = 0; i < 8; ++i)
    pmw[((size_t)b * 128 + d) * 256 + (t0 + tl0 + i * 2)] = acc[i];
}

struct KParams {
  const float* memory;
  const int* mlen;
  const float* convW;
  const float* ldW;
  const float* attnv;
  const float* projW;
  const float* projb;
  const float* gateW;
  const float* gateb;
  char* wsb;
  float* out;
};

// ---------------- main persistent kernel ----------------
__global__ void __launch_bounds__(512, 2) k_main(KParams p) {
  const int th = threadIdx.x;
  const int bk = blockIdx.x;
  char* wsb = p.wsb;
  const int l = th & 63, w = th >> 6;
  u32* barr = (u32*)(wsb + OFF_BAR);
  u32* flg  = (u32*)(wsb + OFF_BAR + 16384);
  u32 ep = 0;

  __shared__ float smC[4608];
  __shared__ float s2q[128], s2v[128];
  __shared__ float s2ldw[4608];               // [128][36] f32 (16B-aligned rows)
  __shared__ float s_conv[8448];              // [256][33]
  __shared__ __align__(16) float s2ah[1024];
  __shared__ float s_e[256], s3wr[4];
  __shared__ float s1cw[1984];                // convW 32*62
  __shared__ float s_aw[256], s_awc[256];     // persistent attention state (per-b block)

  const float* pmT = (const float*)(wsb + OFF_PM);
  const u16* qwb = (const u16*)(wsb + OFF_QWB);
  const float* biasD = (const float*)(wsb + OFF_BD);

  // persistent LDS staging (step-invariant)
  for (int i = th; i < 1984; i += 512) s1cw[i] = p.convW[i];
  for (int i = th; i < 4096; i += 512) s2ldw[(i >> 5) * 36 + (i & 31)] = p.ldW[i];
  if (th < 128) s2v[th] = p.attnv[th];
  if (th < 256) { s_aw[th] = 0.f; s_awc[th] = 0.f; }

  // per-thread attn bias (th<256)
  float biasAr = 0.f;
  if (th < 256) {
    int r = th >> 4;
    biasAr = ((const float*)(wsb + OFF_BA))[(r >> 2) * 1024 + bk * 4 + (r & 3)];
  }
  int len = 0;
  if (bk < 16) len = p.mlen[bk];
  float cA = 0.f, cD = 0.f;   // register cell states (cA: th<64 all blocks; cD: th<128 dec blocks)

  // preload step-invariant attn A-fragments only (7 tiles/wave, 28 VGPRs)
  short8 afA[7];
  {
    const char* wfa = wsb + OFF_WFA;
#pragma unroll
    for (int i = 0; i < 7; ++i)
      afA[i] = *(const short8*)(wfa + (((size_t)bk * 56 + (w + 8 * i)) * 64 + l) * 16);
  }
  __syncthreads();

  // ======== step loop: epoch1 = attn-LSTM(t); epoch2 = attention B(t) || dec(t-1) ========
  for (int t = 0; t <= 64; ++t) {
    const int par = t & 1, par2 = par ^ 1;

    if (t < 64) {
      // ---- epoch 1: attn-LSTM gates (MFMA) + pointwise ----
      short8 bfr[7];
      bfr[0] = *(const short8*)(wsb + OFF_PREF + (((size_t)t * 8 + w) * 64 + l) * 16);
#pragma unroll
      for (int i = 1; i < 7; ++i)
        bfr[i] = ld_frag_agent(wsb + OFF_XBUFA + (size_t)par * 49152 +
                               ((size_t)(w + 8 * i - 8) * 64 + l) * 16);
      f32x4 acc = {0.f, 0.f, 0.f, 0.f};
#pragma unroll
      for (int i = 0; i < 7; ++i)
        acc = __builtin_amdgcn_mfma_f32_16x16x32_bf16(afA[i], bfr[i], acc, 0, 0, 0);
#pragma unroll
      for (int r4 = 0; r4 < 4; ++r4)
        smC[w * 256 + ((l >> 4) * 4 + r4) * 16 + (l & 15)] = acc[r4];
      __syncthreads();
      if (th < 256) {
        int r = th >> 4, b2 = th & 15;
        float s = 0.f;
#pragma unroll
        for (int w2 = 0; w2 < 8; ++w2) s += smC[w2 * 256 + r * 16 + b2];
        smC[4096 + r * 16 + b2] = s + biasAr;
      }
      __syncthreads();
      if (th < 64) {
        int ul = th >> 4, b = th & 15, u = bk * 4 + ul;
        float gi = smC[4096 + ul * 16 + b];
        float gf = smC[4096 + (4 + ul) * 16 + b];
        float gc = smC[4096 + (8 + ul) * 16 + b];
        float go = smC[4096 + (12 + ul) * 16 + b];
        float c2 = sigmf(gf) * cA + sigmf(gi) * tanhf(gc);
        float h2 = sigmf(go) * tanhf(c2);
        cA = c2;
        st_f32_agent((float*)(wsb + OFF_AHN) + b * 1024 + u, h2);
        u16 hb = f2bf(h2);
        st_u16_agent((u16*)(wsb + OFF_XBUFA) + (size_t)par2 * 24576 +
                     (((size_t)(16 + (u >> 5)) * 64 + ((u >> 3) & 3) * 16 + b) * 8 + (u & 7)), hb);
        st_u16_agent((u16*)(wsb + OFF_AHFD) +
                     ((((size_t)(t + 1) * 32 + (u >> 5)) * 64 + ((u >> 3) & 3) * 16 + b) * 8 + (u & 7)), hb);
      }
      gbar(barr, flg, bk, th, ++ep);
    }

    // ---- epoch 2: attention phase B(t) on blocks 0..15; dec-LSTM(t-1) on 128..255 ----
    if (bk < 16 && t < 64) {
      const int b = bk;
      {
        const u64* src = (const u64*)((float*)(wsb + OFF_AHN) + (size_t)b * 1024);
        ((u64*)s2ah)[th] = __hip_atomic_load(src + th, __ATOMIC_RELAXED, __HIP_MEMORY_SCOPE_AGENT);
      }
      __syncthreads();
      {  // query partials
        int d = th & 127, part = th >> 7;
        const u16* qr = qwb + d * 1024 + part * 256;
        const float* ah = s2ah + part * 256;
        float qa = 0.f;
        for (int kk = 0; kk < 256; kk += 8) {
          short8 v = *(const short8*)(qr + kk);
#pragma unroll
          for (int e = 0; e < 8; ++e) qa += bf2f((u16)v[e]) * ah[kk + e];
        }
        smC[part * 128 + d] = qa;
      }
      __syncthreads();
      if (th < 128) s2q[th] = smC[th] + smC[128 + th] + smC[256 + th] + smC[384 + th];
      // conv single-pass, len-bounded
      {
        int jmax = (len + 15) >> 4;
        for (int j = 0; j < jmax; ++j) {
          int idx = j * 512 + th, tt = idx >> 5, f = idx & 31;
          float a = 0.f;
          const float* w0 = s1cw + f * 62;
#pragma unroll
          for (int kk = 0; kk < 31; ++kk) {
            int pos = tt + kk - 15;
            bool ok = (pos >= 0 && pos < 256);
            float awv = ok ? s_aw[pos] : 0.f;
            float awcv = ok ? s_awc[pos] : 0.f;
            a += awv * w0[kk] + awcv * w0[31 + kk];
          }
          s_conv[tt * 33 + f] = a;
        }
      }
      __syncthreads();
      {  // energies: thread = (tt, d-half of 64)
        int tt = th >> 1, dbase = (th & 1) << 6;
        float e = 0.f;
        if (tt < len) {
          float cvr[32];
          const float* cv = s_conv + tt * 33;
#pragma unroll
          for (int f = 0; f < 32; ++f) cvr[f] = cv[f];
          const float* pmr = pmT + ((size_t)b * 128 + dbase) * 256 + tt;
#pragma unroll 2
          for (int jd = 0; jd < 64; ++jd) {
            int d2 = dbase + jd;
            float sacc = s2q[d2] + pmr[(size_t)jd * 256];
            const float4* lw4 = (const float4*)(s2ldw + d2 * 36);
#pragma unroll
            for (int f4 = 0; f4 < 8; ++f4) {
              float4 lw = lw4[f4];
              sacc += cvr[f4 * 4] * lw.x + cvr[f4 * 4 + 1] * lw.y +
                      cvr[f4 * 4 + 2] * lw.z + cvr[f4 * 4 + 3] * lw.w;
            }
            e += s2v[d2] * tanh_fast(sacc);
          }
        }
        e += __shfl_xor(e, 1);
        if ((th & 1) == 0) s_e[tt] = (tt < len) ? __expf(e) : 0.f;
      }
      __syncthreads();
      if (th < 256) {
        float v0 = s_e[th];
#pragma unroll
        for (int off = 32; off; off >>= 1) v0 += __shfl_xor(v0, off);
        if ((th & 63) == 0) s3wr[th >> 6] = v0;
      }
      __syncthreads();
      float rden = 1.f / (s3wr[0] + s3wr[1] + s3wr[2] + s3wr[3]);
      if (th < 256) {
        float a = s_e[th] * rden;
        s_aw[th] = a;
        s_awc[th] += a;
        p.out[82944 + ((size_t)(b * 64 + t)) * 256 + th] = a;
      }
      __syncthreads();
      {  // context from f16 memory copy
        const int d = th;
        const _Float16* mb = (const _Float16*)(wsb + OFF_MF16) + (size_t)b * 131072 + d;
        float a0 = 0.f, a1 = 0.f, a2 = 0.f, a3 = 0.f;
        int lim4 = (len + 3) & ~3;
        for (int tt = 0; tt < lim4; tt += 4) {
          a0 += s_aw[tt] * (float)mb[(size_t)tt * 512];
          a1 += s_aw[tt + 1] * (float)mb[(size_t)(tt + 1) * 512];
          a2 += s_aw[tt + 2] * (float)mb[(size_t)(tt + 2) * 512];
          a3 += s_aw[tt + 3] * (float)mb[(size_t)(tt + 3) * 512];
        }
        float ctxv = (a0 + a1) + (a2 + a3);
        st_f32_agent((float*)(wsb + OFF_CTXF) + ((size_t)(t + 1) * 512 + d) * 16 + b, ctxv);
        u16 cb2 = f2bf(ctxv);
        st_u16_agent((u16*)(wsb + OFF_XBUFA) + (size_t)par2 * 24576 +
                     (((size_t)(d >> 5) * 64 + ((d >> 3) & 3) * 16 + b) * 8 + (d & 7)), cb2);
        st_u16_agent((u16*)(wsb + OFF_CTXFD) +
                     ((((size_t)(t + 1) * 16 + (d >> 5)) * 64 + ((d >> 3) & 3) * 16 + b) * 8 + (d & 7)), cb2);
      }
    } else if (bk >= 128 && t >= 1) {
      // dec-LSTM step td = t-1; block owns 32 gate rows (2 row-tiles), weights from L2
      const int td = t - 1;
      const int ptd = td & 1;
      const int tIdx0 = (bk - 128) * 2;
      const int rt = w & 1, kc = w >> 1;
      const int tIdx = tIdx0 + rt;
      const char* wfd = wsb + OFF_WFD;
      f32x4 acc = {0.f, 0.f, 0.f, 0.f};
#pragma unroll 5
      for (int i = 0; i < 20; ++i) {
        int kt = kc * 20 + i;
        short8 av = *(const short8*)(wfd + (((size_t)tIdx * 80 + kt) * 64 + l) * 16);
        short8 bv;
        if (kt < 32)      bv = ld_frag_agent(wsb + OFF_AHFD + (((size_t)t * 32 + kt) * 64 + l) * 16);
        else if (kt < 48) bv = ld_frag_agent(wsb + OFF_CTXFD + (((size_t)t * 16 + (kt - 32)) * 64 + l) * 16);
        else              bv = ld_frag_agent(wsb + OFF_DHB + (size_t)ptd * 32768 + ((size_t)(kt - 48) * 64 + l) * 16);
        acc = __builtin_amdgcn_mfma_f32_16x16x32_bf16(av, bv, acc, 0, 0, 0);
      }
#pragma unroll
      for (int r4 = 0; r4 < 4; ++r4)
        smC[w * 256 + ((l >> 4) * 4 + r4) * 16 + (l & 15)] = acc[r4];
      __syncthreads();
      {  // reduce 4 k-chunk partials per row-tile; 512 threads = 2 rowtiles x 16 r x 16 b
        int rt2 = th >> 8, r = (th >> 4) & 15, b2 = th & 15;
        float s = 0.f;
#pragma unroll
        for (int q = 0; q < 4; ++q) s += smC[(rt2 + 2 * q) * 256 + r * 16 + b2];
        s += biasD[(r >> 2) * 1024 + (tIdx0 + rt2) * 4 + (r & 3)];
        smC[4096 + th] = s;
      }
      __syncthreads();
      if (th < 128) {
        int b = th & 15, lu = th >> 4;
        int rt3 = lu >> 2, ul = lu & 3;
        int u = (tIdx0 + rt3) * 4 + ul;
        float gi = smC[4096 + rt3 * 256 + ul * 16 + b];
        float gf = smC[4096 + rt3 * 256 + (4 + ul) * 16 + b];
        float gc = smC[4096 + rt3 * 256 + (8 + ul) * 16 + b];
        float go = smC[4096 + rt3 * 256 + (12 + ul) * 16 + b];
        float c2 = sigmf(gf) * cD + sigmf(gi) * tanhf(gc);
        float h2 = sigmf(go) * tanhf(c2);
        cD = c2;
        st_f32_agent((float*)(wsb + OFF_DHF) + ((size_t)t * 1024 + u) * 16 + b, h2);
        st_u16_agent((u16*)(wsb + OFF_DHB) + (size_t)(t & 1) * 16384 +
                     (((size_t)(u >> 5) * 64 + ((u >> 3) & 3) * 16 + b) * 8 + (u & 7)), f2bf(h2));
      }
    }
    gbar(barr, flg, bk, th, ++ep);
  }

  // ================= epilogue: mel + gate projections =================
  // Plain loads OK: DHF/CTXF written once via agent stores (LLC) before the
  // final barrier; any stale L1/L2 lines from a prior replay hold bitwise
  // identical values (deterministic kernel).
  {
    int t = bk & 63, pa = bk >> 6;
    const float* dh = (const float*)(wsb + OFF_DHF) + (size_t)(t + 1) * 16384;
    const float* cx = (const float*)(wsb + OFF_CTXF) + (size_t)(t + 1) * 8192;
    int lim = (pa == 3) ? 336 : 320;
    for (int idx = th; idx < lim; idx += 512) {
      if (idx < 320) {
        int mi = idx >> 4, b = idx & 15, m = pa * 20 + mi;
        const float* wr = p.projW + (size_t)m * 1536;
        float a0 = 0.f, a1 = 0.f;
#pragma unroll 8
        for (int k = 0; k < 1024; k += 2) { a0 += wr[k] * dh[k * 16 + b]; a1 += wr[k + 1] * dh[(k + 1) * 16 + b]; }
#pragma unroll 8
        for (int k = 0; k < 512; k += 2)  { a0 += wr[1024 + k] * cx[k * 16 + b]; a1 += wr[1025 + k] * cx[(k + 1) * 16 + b]; }
        p.out[((size_t)(b * 80 + m)) * 64 + t] = a0 + a1 + p.projb[m];
      } else {
        int b = idx - 320;
        float a0 = 0.f, a1 = 0.f;
#pragma unroll 8
        for (int k = 0; k < 1024; k += 2) { a0 += p.gateW[k] * dh[k * 16 + b]; a1 += p.gateW[k + 1] * dh[(k + 1) * 16 + b]; }
#pragma unroll 8
        for (int k = 0; k < 512; k += 2)  { a0 += p.gateW[1024 + k] * cx[k * 16 + b]; a1 += p.gateW[1025 + k] * cx[(k + 1) * 16 + b]; }
        p.out[81920 + b * 64 + t] = a0 + a1 + p.gateb[0];
      }
    }
  }
}

// ---------------- host launcher ----------------
extern "C" void kernel_launch(void* const* d_in, const int* in_sizes, int n_in,
                              void* d_out, int out_size, void* d_ws, size_t ws_size,
                              hipStream_t stream) {
  (void)in_sizes; (void)n_in; (void)out_size; (void)ws_size;
  const float* memory = (const float*)d_in[0];
  const float* dec_in = (const float*)d_in[1];
  const int*   mlen   = (const int*)d_in[2];
  const float* pW1    = (const float*)d_in[3];
  const float* pb1    = (const float*)d_in[4];
  const float* pW2    = (const float*)d_in[5];
  const float* pb2    = (const float*)d_in[6];
  const float* aWih   = (const float*)d_in[7];
  const float* aWhh   = (const float*)d_in[8];
  const float* abih   = (const float*)d_in[9];
  const float* abhh   = (const float*)d_in[10];
  const float* qW     = (const float*)d_in[11];
  const float* memW   = (const float*)d_in[12];
  const float* convW  = (const float*)d_in[13];
  const float* ldW    = (const float*)d_in[14];
  const float* attnv  = (const float*)d_in[15];
  const float* dWih   = (const float*)d_in[16];
  const float* dWhh   = (const float*)d_in[17];
  const float* dbih   = (const float*)d_in[18];
  const float* dbhh   = (const float*)d_in[19];
  const float* projW  = (const float*)d_in[20];
  const float* projb  = (const float*)d_in[21];
  const float* gateW  = (const float*)d_in[22];
  const float* gateb  = (const float*)d_in[23];
  char* wsb = (char*)d_ws;
  float* out = (float*)d_out;

  hipMemsetAsync(wsb + OFF_XBUFA, 0, ZERO_BYTES, stream);

  hipLaunchKernelGGL(k_wfrag, dim3(3584), dim3(256), 0, stream, aWih, aWhh, wsb + OFF_WFA, 56, 768);
  hipLaunchKernelGGL(k_wfrag, dim3(5120), dim3(256), 0, stream, dWih, dWhh, wsb + OFF_WFD, 80, 1536);
  hipLaunchKernelGGL(k_smallprep, dim3(800), dim3(256), 0, stream, memW, abih, abhh, dbih, dbhh, qW, wsb);
  hipLaunchKernelGGL(k_memf16, dim3(2048), dim3(256), 0, stream, memory, wsb);
  hipLaunchKernelGGL(k_prenet, dim3(64, 16), dim3(256), 0, stream, dec_in, pW1, pb1, pW2, pb2, wsb);
  hipLaunchKernelGGL(k_pm, dim3(256), dim3(256), 0, stream, memory, wsb);

  KParams p{memory, mlen, convW, ldW, attnv, projW, projb, gateW, gateb, wsb, out};
  void* args[] = { &p };
  hipLaunchCooperativeKernel((void*)k_main, dim3(256), dim3(512), args, 0, stream);
}